// Round 1
// baseline (530.870 us; speedup 1.0000x reference)
//
#include <hip/hip_runtime.h>

#define N_NODES 100000
#define N_EDGES 1600000
#define NF 64

// ws layout:
//   A     : [N_NODES][128] f32  (concat A0|A1 per row)         51,200,000 B
//   stats : [128] f64 (sum[64], sumsq[64])                          1,024 B
//   U     : [128][64] f32 (U_k[i][o] = sum_j linear[k][i][j]*mlp_w[o][j])

__global__ __launch_bounds__(256) void prep_U(const float* __restrict__ linear,
                                              const float* __restrict__ mlp_w,
                                              float* __restrict__ U) {
  for (int idx = threadIdx.x; idx < 2 * 64 * 64; idx += 256) {
    int o = idx & 63;
    int ki = idx >> 6;  // k*64 + i
    float acc = 0.f;
#pragma unroll 8
    for (int j = 0; j < 64; ++j)
      acc += linear[ki * 64 + j] * mlp_w[o * 64 + j];
    U[ki * 64 + o] = acc;
  }
}

__global__ __launch_bounds__(256) void scatter_edges(
    const float* __restrict__ feature, const int* __restrict__ esrc,
    const int* __restrict__ edst, const int* __restrict__ eord,
    float* __restrict__ A) {
  const int lane = threadIdx.x & 63;
  int wid = (blockIdx.x * 256 + threadIdx.x) >> 6;
  wid = __builtin_amdgcn_readfirstlane(wid);
  const int nw = gridDim.x * 4;
  for (int e = wid; e < N_EDGES; e += nw) {
    int s = esrc[e];
    int d = edst[e];
    int k = eord[e];
    float v = feature[(size_t)s * 64 + lane];
    atomicAdd(&A[(size_t)d * 128 + k * 64 + lane], v);
  }
}

__global__ __launch_bounds__(256) void gemm_relu(
    const float* __restrict__ A, const float* __restrict__ U,
    const float* __restrict__ bias, float* __restrict__ out) {
  __shared__ float Us[128 * 64];
  for (int i = threadIdx.x; i < 128 * 64; i += 256) Us[i] = U[i];
  __syncthreads();
  int row = blockIdx.x * 256 + threadIdx.x;
  if (row >= N_NODES) return;

  const float4* Ar = reinterpret_cast<const float4*>(A + (size_t)row * 128);
  float acc[64];
#pragma unroll
  for (int o = 0; o < 64; ++o) acc[o] = bias[o];

#pragma unroll 2
  for (int i4 = 0; i4 < 32; ++i4) {
    float4 a = Ar[i4];
    const float* Ur = &Us[i4 * 4 * 64];
    float av[4] = {a.x, a.y, a.z, a.w};
#pragma unroll
    for (int u = 0; u < 4; ++u) {
#pragma unroll
      for (int o = 0; o < 64; ++o)
        acc[o] = fmaf(av[u], Ur[u * 64 + o], acc[o]);
    }
  }

  float4* Or = reinterpret_cast<float4*>(out + (size_t)row * 64);
#pragma unroll
  for (int o4 = 0; o4 < 16; ++o4) {
    float4 r;
    r.x = fmaxf(acc[o4 * 4 + 0], 0.f);
    r.y = fmaxf(acc[o4 * 4 + 1], 0.f);
    r.z = fmaxf(acc[o4 * 4 + 2], 0.f);
    r.w = fmaxf(acc[o4 * 4 + 3], 0.f);
    Or[o4] = r;
  }
}

__global__ __launch_bounds__(256) void bn_stats(const float* __restrict__ h,
                                                double* __restrict__ stats) {
  const int lane = threadIdx.x & 63;
  int wid = (blockIdx.x * 256 + threadIdx.x) >> 6;
  const int nw = gridDim.x * 4;
  double s = 0.0, sq = 0.0;
  for (int r = wid; r < N_NODES; r += nw) {
    float v = h[(size_t)r * 64 + lane];
    s += (double)v;
    sq += (double)v * (double)v;
  }
  atomicAdd(&stats[lane], s);
  atomicAdd(&stats[64 + lane], sq);
}

__global__ __launch_bounds__(256) void bn_apply(float* __restrict__ h,
                                                const double* __restrict__ stats,
                                                const float* __restrict__ gamma,
                                                const float* __restrict__ beta) {
  const int lane = threadIdx.x & 63;
  double mean = stats[lane] * (1.0 / N_NODES);
  double var = stats[64 + lane] * (1.0 / N_NODES) - mean * mean;
  float inv = (float)(1.0 / sqrt(var + 1e-5));
  float scale = gamma[lane] * inv;
  float shift = beta[lane] - (float)mean * scale;
  int wid = (blockIdx.x * 256 + threadIdx.x) >> 6;
  const int nw = gridDim.x * 4;
  for (int r = wid; r < N_NODES; r += nw) {
    size_t idx = (size_t)r * 64 + lane;
    h[idx] = h[idx] * scale + shift;
  }
}

extern "C" void kernel_launch(void* const* d_in, const int* in_sizes, int n_in,
                              void* d_out, int out_size, void* d_ws, size_t ws_size,
                              hipStream_t stream) {
  const float* feature = (const float*)d_in[0];
  // d_in[1] = sp_embeddings (unused by forward)
  const float* linear = (const float*)d_in[2];
  const float* mlp_w  = (const float*)d_in[3];
  const float* mlp_b  = (const float*)d_in[4];
  const float* gamma  = (const float*)d_in[5];
  const float* beta   = (const float*)d_in[6];
  const int* esrc = (const int*)d_in[7];
  const int* edst = (const int*)d_in[8];
  const int* eord = (const int*)d_in[9];
  float* out = (float*)d_out;

  const size_t A_bytes = (size_t)N_NODES * 128 * sizeof(float);  // 51.2 MB
  float* A = (float*)d_ws;
  double* stats = (double*)((char*)d_ws + A_bytes);
  float* U = (float*)((char*)d_ws + A_bytes + 1024);

  hipMemsetAsync(d_ws, 0, A_bytes + 1024, stream);
  prep_U<<<1, 256, 0, stream>>>(linear, mlp_w, U);
  scatter_edges<<<2048, 256, 0, stream>>>(feature, esrc, edst, eord, A);
  gemm_relu<<<(N_NODES + 255) / 256, 256, 0, stream>>>(A, U, mlp_b, out);
  bn_stats<<<512, 256, 0, stream>>>(out, stats);
  bn_apply<<<512, 256, 0, stream>>>(out, stats, gamma, beta);
}

// Round 2
// 490.448 us; speedup vs baseline: 1.0824x; 1.0824x over previous
//
#include <hip/hip_runtime.h>

#define N_NODES 100000
#define N_EDGES 1600000

// ws layout (bytes):
//  cnt   @ 0        : N_NODES u32     (400000)   per-dst edge counts
//  offs  @ 400000   : N_NODES+1 u32   (400004)   CSR row offsets
//  cur   @ 800016   : N_NODES u32     (400000)   working copy for fill
//  bsum  @ 1200016  : 256 u32                    per-scan-block sums
//  bofs  @ 1201040  : 256 u32                    exclusive block offsets
//  stats @ 1202064  : 128 f64                    BN sum / sumsq
//  U     @ 1203088  : 128x64 f32 (32768)         U_k = linear_k @ mlp_w^T
//  pay   @ 1235856  : N_EDGES u32                packed (ord<<20 | src), dst-sorted

#define SCAN_CHUNK 391  // 256 blocks * 391 = 100096 >= 100000

__global__ __launch_bounds__(256) void prep_U(const float* __restrict__ linear,
                                              const float* __restrict__ mlp_w,
                                              float* __restrict__ U) {
  for (int idx = threadIdx.x; idx < 2 * 64 * 64; idx += 256) {
    int o = idx & 63;
    int ki = idx >> 6;  // k*64 + i
    float acc = 0.f;
#pragma unroll 8
    for (int j = 0; j < 64; ++j)
      acc += linear[ki * 64 + j] * mlp_w[o * 64 + j];
    U[ki * 64 + o] = acc;
  }
}

__global__ __launch_bounds__(256) void hist(const int* __restrict__ edst,
                                            unsigned* __restrict__ cnt) {
  int e = blockIdx.x * 256 + threadIdx.x;
  if (e < N_EDGES) atomicAdd(&cnt[edst[e]], 1u);
}

__global__ __launch_bounds__(256) void scanA(const unsigned* __restrict__ cnt,
                                             unsigned* __restrict__ bsum) {
  __shared__ unsigned red[256];
  int start = blockIdx.x * SCAN_CHUNK;
  int end = min(start + SCAN_CHUNK, N_NODES);
  unsigned s = 0;
  for (int i = start + (int)threadIdx.x; i < end; i += 256) s += cnt[i];
  red[threadIdx.x] = s;
  __syncthreads();
  for (int off = 128; off > 0; off >>= 1) {
    if ((int)threadIdx.x < off) red[threadIdx.x] += red[threadIdx.x + off];
    __syncthreads();
  }
  if (threadIdx.x == 0) bsum[blockIdx.x] = red[0];
}

__global__ __launch_bounds__(256) void scanB(const unsigned* __restrict__ bsum,
                                             unsigned* __restrict__ bofs) {
  __shared__ unsigned sh[256];
  sh[threadIdx.x] = bsum[threadIdx.x];
  __syncthreads();
  if (threadIdx.x == 0) {
    unsigned run = 0;
    for (int i = 0; i < 256; ++i) { unsigned v = sh[i]; sh[i] = run; run += v; }
  }
  __syncthreads();
  bofs[threadIdx.x] = sh[threadIdx.x];
}

__global__ __launch_bounds__(256) void scanC(const unsigned* __restrict__ cnt,
                                             const unsigned* __restrict__ bofs,
                                             unsigned* __restrict__ offs,
                                             unsigned* __restrict__ cur) {
  __shared__ unsigned sh[256];
  const int t = threadIdx.x;
  int start = blockIdx.x * SCAN_CHUNK;
  int count = min(SCAN_CHUNK, N_NODES - start);
  int lo = t * 2, hi = min(count, lo + 2);  // each thread covers <=2 elems
  unsigned s = 0;
  for (int i = lo; i < hi; ++i) s += cnt[start + i];
  sh[t] = s;
  __syncthreads();
#pragma unroll
  for (int off = 1; off < 256; off <<= 1) {
    unsigned v = (t >= off) ? sh[t - off] : 0u;
    __syncthreads();
    sh[t] += v;
    __syncthreads();
  }
  unsigned run = bofs[blockIdx.x] + sh[t] - s;  // exclusive within block
  for (int i = lo; i < hi; ++i) {
    offs[start + i] = run;
    cur[start + i] = run;
    run += cnt[start + i];
  }
  if (blockIdx.x == 255 && t == 0) offs[N_NODES] = N_EDGES;
}

__global__ __launch_bounds__(256) void fill(const int* __restrict__ esrc,
                                            const int* __restrict__ edst,
                                            const int* __restrict__ eord,
                                            unsigned* __restrict__ cur,
                                            unsigned* __restrict__ pay) {
  int e = blockIdx.x * 256 + threadIdx.x;
  if (e < N_EDGES) {
    int d = edst[e];
    unsigned pos = atomicAdd(&cur[d], 1u);
    pay[pos] = (unsigned)esrc[e] | ((unsigned)eord[e] << 20);
  }
}

// One wave per node: gather feature rows of incoming edges (L3-resident),
// accumulate a0/a1 per lane, LDS-transpose, matvec vs U (in VGPRs),
// bias+ReLU, write out, accumulate BN stats (block-reduced, 1 atomic/chan/block).
__global__ __launch_bounds__(256) void gather(const unsigned* __restrict__ offs,
                                              const unsigned* __restrict__ pay,
                                              const float* __restrict__ feature,
                                              const float* __restrict__ U,
                                              const float* __restrict__ bias,
                                              float* __restrict__ out,
                                              double* __restrict__ stats) {
  __shared__ float a_lds[4][128];
  __shared__ double dred[4][64];
  const int lane = threadIdx.x & 63;
  const int w = threadIdx.x >> 6;

  float Ur[128];
#pragma unroll
  for (int i = 0; i < 128; ++i) Ur[i] = U[i * 64 + lane];
  const float bo = bias[lane];

  double s0 = 0.0, s1 = 0.0;
  int wid = blockIdx.x * 4 + w;
  const int nw = gridDim.x * 4;

  for (int n = wid; n < N_NODES; n += nw) {
    unsigned beg = offs[n], end = offs[n + 1];
    float a0 = 0.f, a1 = 0.f;
    unsigned e = beg;
    for (; e + 8 <= end; e += 8) {
      unsigned p[8];
#pragma unroll
      for (int j = 0; j < 8; ++j) p[j] = pay[e + j];
      float v[8];
#pragma unroll
      for (int j = 0; j < 8; ++j)
        v[j] = feature[(size_t)(p[j] & 0xFFFFFu) * 64 + lane];
#pragma unroll
      for (int j = 0; j < 8; ++j) {
        if (p[j] & (1u << 20)) a1 += v[j]; else a0 += v[j];
      }
    }
    for (; e < end; ++e) {
      unsigned p = pay[e];
      float v = feature[(size_t)(p & 0xFFFFFu) * 64 + lane];
      if (p & (1u << 20)) a1 += v; else a0 += v;
    }

    // wave-local transpose through LDS
    a_lds[w][lane] = a0;
    a_lds[w][64 + lane] = a1;
    asm volatile("s_waitcnt lgkmcnt(0)" ::: "memory");
    __builtin_amdgcn_sched_barrier(0);

    float acc = bo;
#pragma unroll
    for (int i4 = 0; i4 < 32; ++i4) {
      float4 a = *reinterpret_cast<const float4*>(&a_lds[w][i4 * 4]);
      acc = fmaf(a.x, Ur[i4 * 4 + 0], acc);
      acc = fmaf(a.y, Ur[i4 * 4 + 1], acc);
      acc = fmaf(a.z, Ur[i4 * 4 + 2], acc);
      acc = fmaf(a.w, Ur[i4 * 4 + 3], acc);
    }
    acc = fmaxf(acc, 0.f);
    out[(size_t)n * 64 + lane] = acc;
    s0 += (double)acc;
    s1 += (double)acc * (double)acc;
  }

  // block-level BN stats reduction: 4 waves -> 1 atomic per channel
  dred[w][lane] = s0;
  __syncthreads();
  if (w == 0) {
    double t = dred[0][lane] + dred[1][lane] + dred[2][lane] + dred[3][lane];
    atomicAdd(&stats[lane], t);
  }
  __syncthreads();
  dred[w][lane] = s1;
  __syncthreads();
  if (w == 0) {
    double t = dred[0][lane] + dred[1][lane] + dred[2][lane] + dred[3][lane];
    atomicAdd(&stats[64 + lane], t);
  }
}

__global__ __launch_bounds__(256) void bn_apply(float* __restrict__ h,
                                                const double* __restrict__ stats,
                                                const float* __restrict__ gamma,
                                                const float* __restrict__ beta) {
  const int lane = threadIdx.x & 63;
  double mean = stats[lane] * (1.0 / N_NODES);
  double var = stats[64 + lane] * (1.0 / N_NODES) - mean * mean;
  float inv = (float)(1.0 / sqrt(var + 1e-5));
  float scale = gamma[lane] * inv;
  float shift = beta[lane] - (float)mean * scale;
  int wid = (blockIdx.x * 256 + threadIdx.x) >> 6;
  const int nw = gridDim.x * 4;
  for (int r = wid; r < N_NODES; r += nw) {
    size_t idx = (size_t)r * 64 + lane;
    h[idx] = h[idx] * scale + shift;
  }
}

extern "C" void kernel_launch(void* const* d_in, const int* in_sizes, int n_in,
                              void* d_out, int out_size, void* d_ws, size_t ws_size,
                              hipStream_t stream) {
  const float* feature = (const float*)d_in[0];
  // d_in[1] = sp_embeddings (unused)
  const float* linear = (const float*)d_in[2];
  const float* mlp_w  = (const float*)d_in[3];
  const float* mlp_b  = (const float*)d_in[4];
  const float* gamma  = (const float*)d_in[5];
  const float* beta   = (const float*)d_in[6];
  const int* esrc = (const int*)d_in[7];
  const int* edst = (const int*)d_in[8];
  const int* eord = (const int*)d_in[9];
  float* out = (float*)d_out;

  char* base = (char*)d_ws;
  unsigned* cnt  = (unsigned*)(base);
  unsigned* offs = (unsigned*)(base + 400000);
  unsigned* cur  = (unsigned*)(base + 800016);
  unsigned* bsum = (unsigned*)(base + 1200016);
  unsigned* bofs = (unsigned*)(base + 1201040);
  double*   stats= (double*)  (base + 1202064);
  float*    U    = (float*)   (base + 1203088);
  unsigned* pay  = (unsigned*)(base + 1235856);

  hipMemsetAsync(cnt, 0, 400000, stream);
  hipMemsetAsync(stats, 0, 1024, stream);
  prep_U<<<1, 256, 0, stream>>>(linear, mlp_w, U);
  hist<<<(N_EDGES + 255) / 256, 256, 0, stream>>>(edst, cnt);
  scanA<<<256, 256, 0, stream>>>(cnt, bsum);
  scanB<<<1, 256, 0, stream>>>(bsum, bofs);
  scanC<<<256, 256, 0, stream>>>(cnt, bofs, offs, cur);
  fill<<<(N_EDGES + 255) / 256, 256, 0, stream>>>(esrc, edst, eord, cur, pay);
  gather<<<512, 256, 0, stream>>>(offs, pay, feature, U, mlp_b, out, stats);
  bn_apply<<<512, 256, 0, stream>>>(out, stats, gamma, beta);
}

// Round 3
// 472.341 us; speedup vs baseline: 1.1239x; 1.0383x over previous
//
#include <hip/hip_runtime.h>

#define N_NODES 100000
#define N_EDGES 1600000

// ws layout (bytes):
//  cnt   @ 0        : N_NODES u32                per-dst edge counts
//  offs  @ 400000   : N_NODES+1 u32              CSR row offsets
//  cur   @ 800016   : N_NODES u32                working copy for fill
//  bsum  @ 1200016  : 256 u32
//  bofs  @ 1201040  : 256 u32
//  stats @ 1202064  : 128 f64                    BN sum / sumsq
//  U     @ 1203088  : 64x128 f32 (32768)         U[i][k*64+o] = sum_j linear[k][i][j]*mlp_w[o][j]
//  pay   @ 1235856  : N_EDGES u32                packed (src<<1 | ord), dst-sorted
//  B     @ 7635856  : N_NODES x 128 bf16 (25.6MB) B[n][k*64+o] = feature[n] . U[:,k*64+o]

#define SCAN_CHUNK 391  // 256 blocks * 391 = 100096 >= 100000

__device__ __forceinline__ unsigned short f2bf(float x) {
  unsigned u = __float_as_uint(x);
  unsigned r = (u + 0x7FFFu + ((u >> 16) & 1u)) >> 16;
  return (unsigned short)r;
}

__global__ __launch_bounds__(256) void prep_U(const float* __restrict__ linear,
                                              const float* __restrict__ mlp_w,
                                              float* __restrict__ U) {
  for (int idx = threadIdx.x; idx < 2 * 64 * 64; idx += 256) {
    int o = idx & 63;
    int ki = idx >> 6;  // k*64 + i
    int k = ki >> 6, i = ki & 63;
    float acc = 0.f;
#pragma unroll 8
    for (int j = 0; j < 64; ++j)
      acc += linear[ki * 64 + j] * mlp_w[o * 64 + j];
    U[i * 128 + k * 64 + o] = acc;
  }
}

__global__ __launch_bounds__(256) void hist(const int* __restrict__ edst,
                                            unsigned* __restrict__ cnt) {
  int e = blockIdx.x * 256 + threadIdx.x;
  if (e < N_EDGES) atomicAdd(&cnt[edst[e]], 1u);
}

__global__ __launch_bounds__(256) void scanA(const unsigned* __restrict__ cnt,
                                             unsigned* __restrict__ bsum) {
  __shared__ unsigned red[256];
  int start = blockIdx.x * SCAN_CHUNK;
  int end = min(start + SCAN_CHUNK, N_NODES);
  unsigned s = 0;
  for (int i = start + (int)threadIdx.x; i < end; i += 256) s += cnt[i];
  red[threadIdx.x] = s;
  __syncthreads();
  for (int off = 128; off > 0; off >>= 1) {
    if ((int)threadIdx.x < off) red[threadIdx.x] += red[threadIdx.x + off];
    __syncthreads();
  }
  if (threadIdx.x == 0) bsum[blockIdx.x] = red[0];
}

__global__ __launch_bounds__(256) void scanB(const unsigned* __restrict__ bsum,
                                             unsigned* __restrict__ bofs) {
  __shared__ unsigned sh[256];
  sh[threadIdx.x] = bsum[threadIdx.x];
  __syncthreads();
  if (threadIdx.x == 0) {
    unsigned run = 0;
    for (int i = 0; i < 256; ++i) { unsigned v = sh[i]; sh[i] = run; run += v; }
  }
  __syncthreads();
  bofs[threadIdx.x] = sh[threadIdx.x];
}

__global__ __launch_bounds__(256) void scanC(const unsigned* __restrict__ cnt,
                                             const unsigned* __restrict__ bofs,
                                             unsigned* __restrict__ offs,
                                             unsigned* __restrict__ cur) {
  __shared__ unsigned sh[256];
  const int t = threadIdx.x;
  int start = blockIdx.x * SCAN_CHUNK;
  int count = min(SCAN_CHUNK, N_NODES - start);
  int lo = t * 2, hi = min(count, lo + 2);
  unsigned s = 0;
  for (int i = lo; i < hi; ++i) s += cnt[start + i];
  sh[t] = s;
  __syncthreads();
#pragma unroll
  for (int off = 1; off < 256; off <<= 1) {
    unsigned v = (t >= off) ? sh[t - off] : 0u;
    __syncthreads();
    sh[t] += v;
    __syncthreads();
  }
  unsigned run = bofs[blockIdx.x] + sh[t] - s;
  for (int i = lo; i < hi; ++i) {
    offs[start + i] = run;
    cur[start + i] = run;
    run += cnt[start + i];
  }
  if (blockIdx.x == 255 && t == 0) offs[N_NODES] = N_EDGES;
}

__global__ __launch_bounds__(256) void fill(const int* __restrict__ esrc,
                                            const int* __restrict__ edst,
                                            const int* __restrict__ eord,
                                            unsigned* __restrict__ cur,
                                            unsigned* __restrict__ pay) {
  int e = blockIdx.x * 256 + threadIdx.x;
  if (e < N_EDGES) {
    int d = edst[e];
    unsigned pos = atomicAdd(&cur[d], 1u);
    pay[pos] = ((unsigned)esrc[e] << 1) | (unsigned)eord[e];
  }
}

// B[n][k*64+o] = sum_i feature[n][i] * U[i][k*64+o], stored bf16
__global__ __launch_bounds__(256) void prep_B(const float* __restrict__ feature,
                                              const float* __restrict__ U,
                                              unsigned short* __restrict__ B) {
  __shared__ float Us[64 * 128];
  for (int i = threadIdx.x; i < 64 * 128; i += 256) Us[i] = U[i];
  __syncthreads();
  int row = blockIdx.x * 256 + threadIdx.x;
  if (row >= N_NODES) return;
  const float4* Fr = reinterpret_cast<const float4*>(feature + (size_t)row * 64);
#pragma unroll
  for (int k = 0; k < 2; ++k) {
    float acc[64];
#pragma unroll
    for (int o = 0; o < 64; ++o) acc[o] = 0.f;
#pragma unroll 4
    for (int i4 = 0; i4 < 16; ++i4) {
      float4 a = Fr[i4];
      float av[4] = {a.x, a.y, a.z, a.w};
#pragma unroll
      for (int u = 0; u < 4; ++u) {
        const float* Ur = &Us[(i4 * 4 + u) * 128 + k * 64];
#pragma unroll
        for (int o = 0; o < 64; ++o) acc[o] = fmaf(av[u], Ur[o], acc[o]);
      }
    }
    ushort4* Bp = reinterpret_cast<ushort4*>(B + (size_t)row * 128 + k * 64);
#pragma unroll
    for (int o4 = 0; o4 < 16; ++o4) {
      ushort4 pk;
      pk.x = f2bf(acc[o4 * 4 + 0]);
      pk.y = f2bf(acc[o4 * 4 + 1]);
      pk.z = f2bf(acc[o4 * 4 + 2]);
      pk.w = f2bf(acc[o4 * 4 + 3]);
      Bp[o4] = pk;
    }
  }
}

// One wave per node: sum bf16 rows B[pay[e]] (L3-resident), + bias, ReLU,
// write out, BN-stat partials (block-reduced, 1 atomic/chan/block).
__global__ __launch_bounds__(256) void gather(const unsigned* __restrict__ offs,
                                              const unsigned* __restrict__ pay,
                                              const unsigned short* __restrict__ B,
                                              const float* __restrict__ bias,
                                              float* __restrict__ out,
                                              double* __restrict__ stats) {
  __shared__ double dred[4][64];
  const int lane = threadIdx.x & 63;
  const int w = threadIdx.x >> 6;
  const float bo = bias[lane];

  double s0 = 0.0, s1 = 0.0;
  int wid = blockIdx.x * 4 + w;
  const int nw = gridDim.x * 4;

  for (int n = wid; n < N_NODES; n += nw) {
    unsigned beg = (unsigned)__builtin_amdgcn_readfirstlane((int)offs[n]);
    unsigned end = (unsigned)__builtin_amdgcn_readfirstlane((int)offs[n + 1]);
    float a = 0.f;
    unsigned e = beg;
    for (; e + 8 <= end; e += 8) {
      unsigned p[8];
#pragma unroll
      for (int j = 0; j < 8; ++j) p[j] = pay[e + j];
      unsigned short v[8];
#pragma unroll
      for (int j = 0; j < 8; ++j) v[j] = B[(size_t)p[j] * 64 + lane];
#pragma unroll
      for (int j = 0; j < 8; ++j)
        a += __uint_as_float((unsigned)v[j] << 16);
    }
    for (; e < end; ++e) {
      unsigned p = pay[e];
      a += __uint_as_float((unsigned)B[(size_t)p * 64 + lane] << 16);
    }
    float acc = fmaxf(a + bo, 0.f);
    out[(size_t)n * 64 + lane] = acc;
    s0 += (double)acc;
    s1 += (double)acc * (double)acc;
  }

  dred[w][lane] = s0;
  __syncthreads();
  if (w == 0) {
    double t = dred[0][lane] + dred[1][lane] + dred[2][lane] + dred[3][lane];
    atomicAdd(&stats[lane], t);
  }
  __syncthreads();
  dred[w][lane] = s1;
  __syncthreads();
  if (w == 0) {
    double t = dred[0][lane] + dred[1][lane] + dred[2][lane] + dred[3][lane];
    atomicAdd(&stats[64 + lane], t);
  }
}

__global__ __launch_bounds__(256) void bn_apply(float* __restrict__ h,
                                                const double* __restrict__ stats,
                                                const float* __restrict__ gamma,
                                                const float* __restrict__ beta) {
  const int lane = threadIdx.x & 63;
  double mean = stats[lane] * (1.0 / N_NODES);
  double var = stats[64 + lane] * (1.0 / N_NODES) - mean * mean;
  float inv = (float)(1.0 / sqrt(var + 1e-5));
  float scale = gamma[lane] * inv;
  float shift = beta[lane] - (float)mean * scale;
  int wid = (blockIdx.x * 256 + threadIdx.x) >> 6;
  const int nw = gridDim.x * 4;
  for (int r = wid; r < N_NODES; r += nw) {
    size_t idx = (size_t)r * 64 + lane;
    h[idx] = h[idx] * scale + shift;
  }
}

extern "C" void kernel_launch(void* const* d_in, const int* in_sizes, int n_in,
                              void* d_out, int out_size, void* d_ws, size_t ws_size,
                              hipStream_t stream) {
  const float* feature = (const float*)d_in[0];
  // d_in[1] = sp_embeddings (unused)
  const float* linear = (const float*)d_in[2];
  const float* mlp_w  = (const float*)d_in[3];
  const float* mlp_b  = (const float*)d_in[4];
  const float* gamma  = (const float*)d_in[5];
  const float* beta   = (const float*)d_in[6];
  const int* esrc = (const int*)d_in[7];
  const int* edst = (const int*)d_in[8];
  const int* eord = (const int*)d_in[9];
  float* out = (float*)d_out;

  char* base = (char*)d_ws;
  unsigned*       cnt  = (unsigned*)(base);
  unsigned*       offs = (unsigned*)(base + 400000);
  unsigned*       cur  = (unsigned*)(base + 800016);
  unsigned*       bsum = (unsigned*)(base + 1200016);
  unsigned*       bofs = (unsigned*)(base + 1201040);
  double*         stats= (double*)  (base + 1202064);
  float*          U    = (float*)   (base + 1203088);
  unsigned*       pay  = (unsigned*)(base + 1235856);
  unsigned short* B    = (unsigned short*)(base + 7635856);

  hipMemsetAsync(cnt, 0, 400000, stream);
  hipMemsetAsync(stats, 0, 1024, stream);
  prep_U<<<1, 256, 0, stream>>>(linear, mlp_w, U);
  hist<<<(N_EDGES + 255) / 256, 256, 0, stream>>>(edst, cnt);
  scanA<<<256, 256, 0, stream>>>(cnt, bsum);
  scanB<<<1, 256, 0, stream>>>(bsum, bofs);
  scanC<<<256, 256, 0, stream>>>(cnt, bofs, offs, cur);
  fill<<<(N_EDGES + 255) / 256, 256, 0, stream>>>(esrc, edst, eord, cur, pay);
  prep_B<<<(N_NODES + 255) / 256, 256, 0, stream>>>(feature, U, B);
  gather<<<4096, 256, 0, stream>>>(offs, pay, B, mlp_b, out, stats);
  bn_apply<<<1024, 256, 0, stream>>>(out, stats, gamma, beta);
}